// Round 7
// baseline (1637.501 us; speedup 1.0000x reference)
//
#include <hip/hip_runtime.h>
#include <cstddef>

// DecoderLayer: T=4, B=4, N=512, D=512, F=2048, H=8, head_dim=64
// I/O: float32. Spike intermediates: bf16 (exact for {0,1,2}).
// f64 MFMA GEMMs (absmax 0.0 proven rounds 3-6).
// Round 7: LDS double-buffering -> ONE barrier per k-tile (was 2); ds_writes
// of tile k+1 interleave with MFMAs of tile k. Keeps round-6 64x64 tile,
// register prefetch, f32-B LDS, fused multi-output dispatches.
#define T_STEPS 4
#define BN 2048                    /* B*N rows per time plane */
#define N_TOK 512
#define D_DIM 512
#define F_DIM 2048

#define MODE_SPK 0
#define MODE_SPK_ADD 1
#define MODE_OUT 2

typedef double d4 __attribute__((ext_vector_type(4)));

__device__ __forceinline__ float bf2f(unsigned short u) {
  unsigned int x = ((unsigned int)u) << 16;
  float f;
  __builtin_memcpy(&f, &x, 4);
  return f;
}
__device__ __forceinline__ unsigned short f2bf(float f) {
  unsigned int x;
  __builtin_memcpy(&x, &f, 4);
  x += 0x7fffu + ((x >> 16) & 1u);  // round to nearest even
  return (unsigned short)(x >> 16);
}

// ---------------------------------------------------------------------------
// MFMA-f64 fused GEMM + LIF over T (round-6 structure + LDS double-buffer).
// Block tile: 64 cols x 64 rows, tile-row r = t*16 + bn_local.
// 4 waves: wr=w>>1 (row half), wc=w&1 (col half); wave tile 32x32 = 2x2
// 16x16 mfma tiles; m-tile mt covers t = wr*2 + mt.
// C/D 16x16 layout: col=lane&15, row=(lane>>4)*4+j (verified, absmax 0.0).
// Multi-output: sel = blockIdx.x/nxb picks (W,bias,out) triple.
// LDS: two buffers of [A f64 16x64 stride 67 | B f32 16x64 stride 72]
// = 1648 doubles each (26.4 KB total). Epilogue overlays UX[16][128] on it.
// Grid: (nxb * ngemm, BN/16), block 256.
// ---------------------------------------------------------------------------
__global__ __launch_bounds__(256) void gemm_lif(
    const void* __restrict__ A1v,
    const unsigned short* __restrict__ A2,     // nullable bf16 spike-sum
    const float* __restrict__ Wa, const float* __restrict__ Wb,
    const float* __restrict__ Wc,
    const float* __restrict__ ba, const float* __restrict__ bb,
    const float* __restrict__ bc,
    const unsigned short* Sprev,               // mode 1 (may alias out)
    const float* __restrict__ Xres,            // mode 2
    const unsigned short* __restrict__ S12,    // mode 2
    void* outa, void* outb, void* outc,
    int N, int K, int nxb, int mode, int a1bf) {
  __shared__ double smem[3296];                // 2 x 1648 doubles = 26368 B
#define AS(b, k, r) smem[(size_t)(b) * 1648 + (size_t)(k) * 67 + (r)]
#define BSF(b, k, c) \
  (((float*)(smem + (size_t)(b) * 1648 + 1072))[(size_t)(k) * 72 + (c)])
#define UX(i, p) smem[(size_t)(i) * 128 + (p)]

  const int sel = (int)blockIdx.x / nxb;       // 0..2
  const int nb = (int)blockIdx.x - sel * nxb;
  const float* W = (sel == 0) ? Wa : ((sel == 1) ? Wb : Wc);
  const float* bias = (sel == 0) ? ba : ((sel == 1) ? bb : bc);
  void* outv = (sel == 0) ? outa : ((sel == 1) ? outb : outc);

  const int tid = threadIdx.x;
  const int lane = tid & 63;
  const int wave = tid >> 6;
  const int wr = wave >> 1, wc = wave & 1;
  const int lm = lane & 15;        // A-row / B-col / C-col index
  const int kl = lane >> 4;        // k-slice 0..3 within mfma
  const int n0 = nb * 64;
  const int bn0 = blockIdx.y * 16;

  // A staging: tile-row r_s = tid>>2 (0..63), k-quad kq_s = (tid&3)*4
  const int r_s = tid >> 2;
  const int kq_s = (tid & 3) * 4;
  const size_t arow = (size_t)((r_s >> 4) * BN + bn0 + (r_s & 15)) * K;
  // B staging: k-row kb = tid>>4 (0..15), col-quad nq = (tid&15)*4
  const int kb = tid >> 4;
  const int nq = (tid & 15) * 4;

  d4 acc00 = {0.0, 0.0, 0.0, 0.0};
  d4 acc01 = {0.0, 0.0, 0.0, 0.0};
  d4 acc10 = {0.0, 0.0, 0.0, 0.0};
  d4 acc11 = {0.0, 0.0, 0.0, 0.0};

  // prefetch registers
  float4 aF = {0.f, 0.f, 0.f, 0.f};
  ushort4 aU = {0, 0, 0, 0};
  ushort4 s4 = {0, 0, 0, 0};
  float4 wv;

#define LOAD_TILE(K0)                                                       \
  do {                                                                      \
    if (a1bf)                                                               \
      aU = *reinterpret_cast<const ushort4*>(                               \
          (const unsigned short*)A1v + arow + (K0) + kq_s);                 \
    else                                                                    \
      aF = *reinterpret_cast<const float4*>(                                \
          (const float*)A1v + arow + (K0) + kq_s);                          \
    if (A2 != nullptr)                                                      \
      s4 = *reinterpret_cast<const ushort4*>(A2 + arow + (K0) + kq_s);      \
    wv = *reinterpret_cast<const float4*>(W + (size_t)((K0) + kb) * N +     \
                                          n0 + nq);                         \
  } while (0)

#define STAGE_TO(BUF)                                                       \
  do {                                                                      \
    double ad[4];                                                           \
    if (a1bf) {                                                             \
      ad[0] = (double)bf2f(aU.x); ad[1] = (double)bf2f(aU.y);               \
      ad[2] = (double)bf2f(aU.z); ad[3] = (double)bf2f(aU.w);               \
    } else {                                                                \
      ad[0] = (double)aF.x; ad[1] = (double)aF.y;                           \
      ad[2] = (double)aF.z; ad[3] = (double)aF.w;                           \
    }                                                                       \
    if (A2 != nullptr) {                                                    \
      ad[0] += (double)bf2f(s4.x); ad[1] += (double)bf2f(s4.y);             \
      ad[2] += (double)bf2f(s4.z); ad[3] += (double)bf2f(s4.w);             \
    }                                                                       \
    AS(BUF, kq_s + 0, r_s) = ad[0];                                         \
    AS(BUF, kq_s + 1, r_s) = ad[1];                                         \
    AS(BUF, kq_s + 2, r_s) = ad[2];                                         \
    AS(BUF, kq_s + 3, r_s) = ad[3];                                         \
    BSF(BUF, kb, nq + 0) = wv.x;                                            \
    BSF(BUF, kb, nq + 1) = wv.y;                                            \
    BSF(BUF, kb, nq + 2) = wv.z;                                            \
    BSF(BUF, kb, nq + 3) = wv.w;                                            \
  } while (0)

  // Pre-loop: fill buffer 0, prefetch tile 1.
  LOAD_TILE(0);
  STAGE_TO(0);
  if (16 < K) LOAD_TILE(16);
  __syncthreads();

  int cur = 0;
  for (int k0 = 0; k0 < K; k0 += 16) {
    // stage prefetched tile k0+16 into the other buffer; prefetch k0+32
    if (k0 + 16 < K) {
      STAGE_TO(1 - cur);
      if (k0 + 32 < K) LOAD_TILE(k0 + 32);
    }
    // MFMA from current buffer (interleaves with the ds_writes above)
#pragma unroll
    for (int kc = 0; kc < 4; ++kc) {
      const int kk = kc * 4 + kl;
      double a0 = AS(cur, kk, wr * 32 + lm);
      double a1 = AS(cur, kk, wr * 32 + 16 + lm);
      double b0 = (double)BSF(cur, kk, wc * 32 + lm);
      double b1 = (double)BSF(cur, kk, wc * 32 + 16 + lm);
      acc00 = __builtin_amdgcn_mfma_f64_16x16x4f64(a0, b0, acc00, 0, 0, 0);
      acc01 = __builtin_amdgcn_mfma_f64_16x16x4f64(a0, b1, acc01, 0, 0, 0);
      acc10 = __builtin_amdgcn_mfma_f64_16x16x4f64(a1, b0, acc10, 0, 0, 0);
      acc11 = __builtin_amdgcn_mfma_f64_16x16x4f64(a1, b1, acc11, 0, 0, 0);
    }
    __syncthreads();   // one barrier per k-tile
    cur ^= 1;
  }
#undef LOAD_TILE
#undef STAGE_TO

  // ---- epilogue: waves wr=1 (t=2,3) ship accs via LDS; wr=0 runs LIF ----
  if (wr == 1) {
#pragma unroll
    for (int j = 0; j < 4; ++j) {
      UX(0 + 0 * 4 + j, wc * 64 + lane) = acc00[j];  // mt0 (t=2), nt0
      UX(0 + 1 * 4 + j, wc * 64 + lane) = acc01[j];  // mt0 (t=2), nt1
      UX(8 + 0 * 4 + j, wc * 64 + lane) = acc10[j];  // mt1 (t=3), nt0
      UX(8 + 1 * 4 + j, wc * 64 + lane) = acc11[j];  // mt1 (t=3), nt1
    }
  }
  __syncthreads();
  if (wr == 0) {
    const double bd[2] = {(double)bias[n0 + wc * 32 + lm],
                          (double)bias[n0 + wc * 32 + 16 + lm]};
#pragma unroll
    for (int nt = 0; nt < 2; ++nt) {
      const int col = n0 + wc * 32 + nt * 16 + lm;
      const double bb2 = bd[nt];
#pragma unroll
      for (int j = 0; j < 4; ++j) {
        const int bn = bn0 + kl * 4 + j;
        double u[4];
        u[0] = (nt ? acc01[j] : acc00[j]) + bb2;           // t=0
        u[1] = (nt ? acc11[j] : acc10[j]) + bb2;           // t=1
        u[2] = UX(0 + nt * 4 + j, wc * 64 + lane) + bb2;   // t=2
        u[3] = UX(8 + nt * 4 + j, wc * 64 + lane) + bb2;   // t=3
        double v = 0.0;
#pragma unroll
        for (int t = 0; t < T_STEPS; ++t) {
          v = v + (u[t] - v) * 0.5;
          float s = (v >= 1.0) ? 1.0f : 0.0f;
          v = (v >= 1.0) ? 0.0 : v;
          size_t idx = (size_t)(t * BN + bn) * N + col;
          if (mode == MODE_SPK) {
            ((unsigned short*)outv)[idx] = f2bf(s);
          } else if (mode == MODE_SPK_ADD) {
            ((unsigned short*)outv)[idx] = f2bf(s + bf2f(Sprev[idx]));
          } else {
            ((float*)outv)[idx] =
                (float)((double)Xres[idx] + (double)bf2f(S12[idx]) + (double)s);
          }
        }
      }
    }
  }
#undef AS
#undef BSF
#undef UX
}

// ---------------------------------------------------------------------------
// Spiking attention, reassociated: u = 0.125 * q @ (k^T @ v) per (t,b,h).
// Spikes are 0/1 -> exact integer sums (< 2^24) in f32; identical to the
// reference's (q@k^T)@v order. bf16 spikes in, exact f32 u out. Grid 128.
// ---------------------------------------------------------------------------
__global__ __launch_bounds__(256) void attn_k(const unsigned short* __restrict__ Q,
                                              const unsigned short* __restrict__ K,
                                              const unsigned short* __restrict__ V,
                                              float* __restrict__ O) {
  const int blk = blockIdx.x;
  const int h = blk & 7;
  const int tb = blk >> 3;
  const size_t base = (size_t)tb * (N_TOK * D_DIM) + h * 64;
  const int tid = threadIdx.x;
  const int tx = tid & 15, ty = tid >> 4;

  __shared__ float Kt[64][65];
  __shared__ float Vt[64][65];
  __shared__ float St[64][65];

  float S[4][4] = {};
  for (int mc = 0; mc < N_TOK; mc += 64) {
#pragma unroll
    for (int rr = 0; rr < 4; ++rr) {
      int row = rr * 16 + ty;
      ushort4 k4 = *reinterpret_cast<const ushort4*>(K + base + (size_t)(mc + row) * D_DIM + tx * 4);
      ushort4 v4 = *reinterpret_cast<const ushort4*>(V + base + (size_t)(mc + row) * D_DIM + tx * 4);
      Kt[row][tx * 4 + 0] = bf2f(k4.x); Kt[row][tx * 4 + 1] = bf2f(k4.y);
      Kt[row][tx * 4 + 2] = bf2f(k4.z); Kt[row][tx * 4 + 3] = bf2f(k4.w);
      Vt[row][tx * 4 + 0] = bf2f(v4.x); Vt[row][tx * 4 + 1] = bf2f(v4.y);
      Vt[row][tx * 4 + 2] = bf2f(v4.z); Vt[row][tx * 4 + 3] = bf2f(v4.w);
    }
    __syncthreads();
#pragma unroll 8
    for (int m = 0; m < 64; ++m) {
      float k0 = Kt[m][ty * 4 + 0], k1 = Kt[m][ty * 4 + 1];
      float k2 = Kt[m][ty * 4 + 2], k3 = Kt[m][ty * 4 + 3];
      float v0 = Vt[m][tx * 4 + 0], v1 = Vt[m][tx * 4 + 1];
      float v2 = Vt[m][tx * 4 + 2], v3 = Vt[m][tx * 4 + 3];
      S[0][0] += k0 * v0; S[0][1] += k0 * v1; S[0][2] += k0 * v2; S[0][3] += k0 * v3;
      S[1][0] += k1 * v0; S[1][1] += k1 * v1; S[1][2] += k1 * v2; S[1][3] += k1 * v3;
      S[2][0] += k2 * v0; S[2][1] += k2 * v1; S[2][2] += k2 * v2; S[2][3] += k2 * v3;
      S[3][0] += k3 * v0; S[3][1] += k3 * v1; S[3][2] += k3 * v2; S[3][3] += k3 * v3;
    }
    __syncthreads();
  }
#pragma unroll
  for (int i = 0; i < 4; ++i)
#pragma unroll
    for (int j = 0; j < 4; ++j) St[ty * 4 + i][tx * 4 + j] = S[i][j];
  __syncthreads();

  for (int nb = 0; nb < 8; ++nb) {
#pragma unroll
    for (int rr = 0; rr < 4; ++rr) {
      int row = rr * 16 + ty;
      ushort4 q4 = *reinterpret_cast<const ushort4*>(Q + base + (size_t)(nb * 64 + row) * D_DIM + tx * 4);
      Kt[row][tx * 4 + 0] = bf2f(q4.x); Kt[row][tx * 4 + 1] = bf2f(q4.y);
      Kt[row][tx * 4 + 2] = bf2f(q4.z); Kt[row][tx * 4 + 3] = bf2f(q4.w);
    }
    __syncthreads();
    float o[4][4] = {};
#pragma unroll 16
    for (int i = 0; i < 64; ++i) {
      float q0 = Kt[ty * 4 + 0][i], q1 = Kt[ty * 4 + 1][i];
      float q2 = Kt[ty * 4 + 2][i], q3 = Kt[ty * 4 + 3][i];
      float s0 = St[i][tx * 4 + 0], s1 = St[i][tx * 4 + 1];
      float s2 = St[i][tx * 4 + 2], s3 = St[i][tx * 4 + 3];
      o[0][0] += q0 * s0; o[0][1] += q0 * s1; o[0][2] += q0 * s2; o[0][3] += q0 * s3;
      o[1][0] += q1 * s0; o[1][1] += q1 * s1; o[1][2] += q1 * s2; o[1][3] += q1 * s3;
      o[2][0] += q2 * s0; o[2][1] += q2 * s1; o[2][2] += q2 * s2; o[2][3] += q2 * s3;
      o[3][0] += q3 * s0; o[3][1] += q3 * s1; o[3][2] += q3 * s2; o[3][3] += q3 * s3;
    }
#pragma unroll
    for (int r = 0; r < 4; ++r) {
      float4 ov;
      ov.x = o[r][0] * 0.125f; ov.y = o[r][1] * 0.125f;
      ov.z = o[r][2] * 0.125f; ov.w = o[r][3] * 0.125f;
      *reinterpret_cast<float4*>(O + base + (size_t)(nb * 64 + ty * 4 + r) * D_DIM + tx * 4) = ov;
    }
    __syncthreads();
  }
}

// ---------------------------------------------------------------------------
// LIF over attention u (exact f32 values, f64 state), writes bf16 spikes.
// ---------------------------------------------------------------------------
__global__ __launch_bounds__(256) void lif_plane(const float* __restrict__ U,
                                                 unsigned short* __restrict__ S) {
  int e = blockIdx.x * 256 + threadIdx.x;
  double v = 0.0;
#pragma unroll
  for (int t = 0; t < T_STEPS; ++t) {
    size_t idx = (size_t)t * (BN * D_DIM) + e;
    double u = (double)U[idx];
    v = v + (u - v) * 0.5;
    float s = (v >= 1.0) ? 1.0f : 0.0f;
    v = (v >= 1.0) ? 0.0 : v;
    S[idx] = f2bf(s);
  }
}

// ---------------------------------------------------------------------------
extern "C" void kernel_launch(void* const* d_in, const int* in_sizes, int n_in,
                              void* d_out, int out_size, void* d_ws, size_t ws_size,
                              hipStream_t stream) {
  const float* x    = (const float*)d_in[0];
  const float* enc  = (const float*)d_in[1];
  const float* Wq_s = (const float*)d_in[2];
  const float* bq_s = (const float*)d_in[3];
  const float* Wk_s = (const float*)d_in[4];
  const float* bk_s = (const float*)d_in[5];
  const float* Wv_s = (const float*)d_in[6];
  const float* bv_s = (const float*)d_in[7];
  const float* Wo_s = (const float*)d_in[8];
  const float* bo_s = (const float*)d_in[9];
  const float* Wq_c = (const float*)d_in[10];
  const float* bq_c = (const float*)d_in[11];
  const float* Wk_c = (const float*)d_in[12];
  const float* bk_c = (const float*)d_in[13];
  const float* Wv_c = (const float*)d_in[14];
  const float* bv_c = (const float*)d_in[15];
  const float* Wo_c = (const float*)d_in[16];
  const float* bo_c = (const float*)d_in[17];
  const float* W1   = (const float*)d_in[18];
  const float* b1   = (const float*)d_in[19];
  const float* W2   = (const float*)d_in[20];
  const float* b2   = (const float*)d_in[21];
  float* out = (float*)d_out;

  // Workspace (48 MB):
  //  0- 8 MB: qs (bf16 [R,D]); later attention spikes as_
  //  8-16 MB: ks;  8-40 MB later h_spk (bf16 [R,F], over ks/vs/u_attn)
  // 16-24 MB: vs
  // 24-40 MB: u_attn (f32 [R,D])
  // 40-48 MB: s1 (bf16 [R,D]) spike-sum of the two attention blocks
  char* pool = (char*)d_ws;
  const size_t MB = 1024 * 1024;
  unsigned short* qs     = (unsigned short*)(pool + 0 * MB);
  unsigned short* ks     = (unsigned short*)(pool + 8 * MB);
  unsigned short* vs     = (unsigned short*)(pool + 16 * MB);
  float*          u_attn = (float*)(pool + 24 * MB);
  unsigned short* as_    = (unsigned short*)(pool + 0 * MB);
  unsigned short* h_spk  = (unsigned short*)(pool + 8 * MB);
  unsigned short* s1     = (unsigned short*)(pool + 40 * MB);

  const unsigned short* NULS = nullptr;
  const float* NULF = nullptr;
  dim3 blk(256);
  int gLif = (BN * D_DIM) / 256;

  // ---- Block 1: self-attention (QKV fused: one dispatch, 3 outputs) ----
  gemm_lif<<<dim3(24, 128), blk, 0, stream>>>(
      x, NULS, Wq_s, Wk_s, Wv_s, bq_s, bk_s, bv_s,
      NULS, NULF, NULS, qs, ks, vs, D_DIM, D_DIM, 8, MODE_SPK, 0);
  attn_k<<<128, blk, 0, stream>>>(qs, ks, vs, u_attn);
  lif_plane<<<gLif, blk, 0, stream>>>(u_attn, as_);
  gemm_lif<<<dim3(8, 128), blk, 0, stream>>>(
      as_, NULS, Wo_s, Wo_s, Wo_s, bo_s, bo_s, bo_s,
      NULS, NULF, NULS, s1, s1, s1, D_DIM, D_DIM, 8, MODE_SPK, 1);

  // ---- Block 2: cross-attention (Q: A=x+s1; K/V fused over enc) ----
  gemm_lif<<<dim3(8, 128), blk, 0, stream>>>(
      x, s1, Wq_c, Wq_c, Wq_c, bq_c, bq_c, bq_c,
      NULS, NULF, NULS, qs, qs, qs, D_DIM, D_DIM, 8, MODE_SPK, 0);
  gemm_lif<<<dim3(16, 128), blk, 0, stream>>>(
      enc, NULS, Wk_c, Wv_c, Wv_c, bk_c, bv_c, bv_c,
      NULS, NULF, NULS, ks, vs, vs, D_DIM, D_DIM, 8, MODE_SPK, 0);
  attn_k<<<128, blk, 0, stream>>>(qs, ks, vs, u_attn);
  lif_plane<<<gLif, blk, 0, stream>>>(u_attn, as_);
  gemm_lif<<<dim3(8, 128), blk, 0, stream>>>(
      as_, NULS, Wo_c, Wo_c, Wo_c, bo_c, bo_c, bo_c,
      s1, NULF, NULS, s1, s1, s1, D_DIM, D_DIM, 8, MODE_SPK_ADD, 1);

  // ---- Block 3: spiking MLP (A = x + s1; final fused residual output) ----
  gemm_lif<<<dim3(32, 128), blk, 0, stream>>>(
      x, s1, W1, W1, W1, b1, b1, b1,
      NULS, NULF, NULS, h_spk, h_spk, h_spk, F_DIM, D_DIM, 32, MODE_SPK, 0);
  gemm_lif<<<dim3(8, 128), blk, 0, stream>>>(
      h_spk, NULS, W2, W2, W2, b2, b2, b2,
      NULS, x, s1, out, out, out, D_DIM, F_DIM, 8, MODE_OUT, 1);

  (void)in_sizes; (void)n_in; (void)out_size; (void)ws_size;
}

// Round 8
// 1086.307 us; speedup vs baseline: 1.5074x; 1.5074x over previous
//
#include <hip/hip_runtime.h>
#include <cstddef>

// DecoderLayer: T=4, B=4, N=512, D=512, F=2048, H=8, head_dim=64
// I/O: float32. Round 8: split-precision bf16-MFMA GEMMs with rigorous
// per-neuron error bounds + f64 recompute of threshold-uncertain neurons.
// W pre-split (wsplit_k) into bf16 hi/mid transposed planes + f32 W^T for
// the fix path. Unflagged spike decisions provably match the f64 reference.
#define T_STEPS 4
#define BN 2048
#define N_TOK 512
#define D_DIM 512
#define F_DIM 2048

#define MODE_SPK 0
#define MODE_SPK_ADD 1
#define MODE_OUT 2

#define FLAG_CAP (2u * 1024u * 1024u)

typedef float f32x4 __attribute__((ext_vector_type(4)));
typedef short s16x8 __attribute__((ext_vector_type(8)));

__device__ __forceinline__ float bf2f(unsigned short u) {
  unsigned int x = ((unsigned int)u) << 16;
  float f;
  __builtin_memcpy(&f, &x, 4);
  return f;
}
__device__ __forceinline__ unsigned short f2bf(float f) {
  unsigned int x;
  __builtin_memcpy(&x, &f, 4);
  x += 0x7fffu + ((x >> 16) & 1u);  // RNE
  return (unsigned short)(x >> 16);
}

// ---------------------------------------------------------------------------
// Weight preprocessing: for each W [K,N] f32 produce WT [N,K] f32 and
// bf16 split planes WhT, WmT [N,K] with w = wh + wm + r, |r| <= 2^-16|w|.
// ---------------------------------------------------------------------------
__global__ __launch_bounds__(256) void wsplit_k(
    const float* w0, const float* w1, const float* w2, const float* w3,
    const float* w4, const float* w5, const float* w6, const float* w7,
    const float* w8, const float* w9,
    float* __restrict__ WT, unsigned short* __restrict__ WhT,
    unsigned short* __restrict__ WmT) {
  __shared__ float T[32][33];
  const int tile = blockIdx.x;
  const float* w;
  int Kd, Nd, lt;
  size_t off;
  if (tile < 2048) {
    const float* ws[8] = {w0, w1, w2, w3, w4, w5, w6, w7};
    int m = tile >> 8;
    lt = tile & 255; Kd = 512; Nd = 512; off = (size_t)m * 262144; w = ws[m];
  } else if (tile < 3072) {
    lt = tile - 2048; Kd = 512; Nd = 2048; off = 2097152; w = w8;
  } else {
    lt = tile - 3072; Kd = 2048; Nd = 512; off = 3145728; w = w9;
  }
  const int tilesK = Kd / 32;
  const int tk = lt % tilesK, tn = lt / tilesK;
  {
    int r = threadIdx.x >> 3, c4 = (threadIdx.x & 7) * 4;
    float4 v = *reinterpret_cast<const float4*>(
        w + (size_t)(tk * 32 + r) * Nd + tn * 32 + c4);
    T[r][c4 + 0] = v.x; T[r][c4 + 1] = v.y;
    T[r][c4 + 2] = v.z; T[r][c4 + 3] = v.w;
  }
  __syncthreads();
  {
    int n = threadIdx.x >> 3, k4 = (threadIdx.x & 7) * 4;
    float wv[4];
#pragma unroll
    for (int j = 0; j < 4; ++j) wv[j] = T[k4 + j][n];
    size_t ob = off + (size_t)(tn * 32 + n) * Kd + tk * 32 + k4;
    float4 o; o.x = wv[0]; o.y = wv[1]; o.z = wv[2]; o.w = wv[3];
    *reinterpret_cast<float4*>(WT + ob) = o;
    ushort4 h, m2;
    unsigned short* hp = &h.x; unsigned short* mp = &m2.x;
#pragma unroll
    for (int j = 0; j < 4; ++j) {
      unsigned short hh = f2bf(wv[j]);
      float r = wv[j] - bf2f(hh);   // exact
      hp[j] = hh; mp[j] = f2bf(r);
    }
    *reinterpret_cast<ushort4*>(WhT + ob) = h;
    *reinterpret_cast<ushort4*>(WmT + ob) = m2;
  }
}

__global__ void zero_k(unsigned int* c) {
  if (threadIdx.x < 8) c[threadIdx.x] = 0u;
}

// ---------------------------------------------------------------------------
// Split-precision bf16-MFMA GEMM + LIF over T + uncertainty flagging.
// Block tile 64 rows (16 bn x 4 t, tile-row r = t*16 + bn_local) x 64 cols.
// Waves: wr=w>>1 row half (t = 2wr+mt), wcq=w&1 col half; wave tile 32x32 =
// 2x2 mfma 16x16x32. C/D: col=lane&15, row=quad*4+j.
// A split on the fly (ah+am); B from pre-split WhT/WmT [N,K].
// Per pair: acc_hi += ah*bh; acc_mid += ah*bm (+ am*bh if !a1bf);
// acc_abs += |ah|*|bh|. u = f64(hi+mid)+bias, E = errC*abs.
// Neurons with |v-1| < 2*errv flagged for f64 recompute (fix_k).
// Grid: (nxb*ngemm, BN/16), block 256.
// ---------------------------------------------------------------------------
__global__ __launch_bounds__(256) void gemm_ns(
    const void* __restrict__ A1v,
    const unsigned short* __restrict__ A2,
    const unsigned short* __restrict__ WhTa, const unsigned short* __restrict__ WhTb,
    const unsigned short* __restrict__ WhTc,
    const unsigned short* __restrict__ WmTa, const unsigned short* __restrict__ WmTb,
    const unsigned short* __restrict__ WmTc,
    const float* __restrict__ ba, const float* __restrict__ bb,
    const float* __restrict__ bc,
    const unsigned short* Sprev, const float* __restrict__ Xres,
    const unsigned short* __restrict__ S12,
    void* outa, void* outb, void* outc,
    unsigned int* __restrict__ cnt, unsigned int* __restrict__ flags,
    int N, int K, int nxb, int mode, int a1bf, float errC) {
  // LDS 20480 B: Ah@0, Am@5120, Bh@10240, Bm@15360; each 64 rows x 32 k bf16,
  // row stride 40 elems (80 B, 16B-aligned, conflict-benign).
  // Epilogue overlay: UXS f32[16][128]@0 (8 KB), UXA @8192 (8 KB).
  __shared__ char smem[20480];

  const int sel = (int)blockIdx.x / nxb;
  const int nb = (int)blockIdx.x - sel * nxb;
  const unsigned short* WhT = sel == 0 ? WhTa : (sel == 1 ? WhTb : WhTc);
  const unsigned short* WmT = sel == 0 ? WmTa : (sel == 1 ? WmTb : WmTc);
  const float* bias = sel == 0 ? ba : (sel == 1 ? bb : bc);
  void* outv = sel == 0 ? outa : (sel == 1 ? outb : outc);

  const int tid = threadIdx.x;
  const int lane = tid & 63;
  const int wave = tid >> 6;
  const int wr = wave >> 1, wcq = wave & 1;
  const int lm = lane & 15, quad = lane >> 4;
  const int n0 = nb * 64;
  const int bn0 = (int)blockIdx.y * 16;

  // staging roles: srow = A tile-row / B tile-col (0..63), skg = k-octet
  const int srow = tid >> 2;
  const int skg = tid & 3;
  const size_t aoff_row = (size_t)((srow >> 4) * BN + bn0 + (srow & 15)) * K;
  const size_t boff_row = (size_t)(n0 + srow) * K;

  f32x4 accH[2][2], accM[2][2], accA[2][2];
#pragma unroll
  for (int i = 0; i < 2; ++i)
#pragma unroll
    for (int j = 0; j < 2; ++j) {
      accH[i][j] = (f32x4){0.f, 0.f, 0.f, 0.f};
      accM[i][j] = (f32x4){0.f, 0.f, 0.f, 0.f};
      accA[i][j] = (f32x4){0.f, 0.f, 0.f, 0.f};
    }

  // prefetch registers
  uint4 paU = {0, 0, 0, 0};
  float4 paF0 = {0, 0, 0, 0}, paF1 = {0, 0, 0, 0};
  uint4 pa2 = {0, 0, 0, 0};
  uint4 pwh, pwm;

#define LOAD_TILE(K0)                                                        \
  do {                                                                       \
    if (a1bf)                                                                \
      paU = *reinterpret_cast<const uint4*>((const unsigned short*)A1v +     \
                                            aoff_row + (K0) + skg * 8);      \
    else {                                                                   \
      const float* A1p = (const float*)A1v + aoff_row + (K0) + skg * 8;      \
      paF0 = *reinterpret_cast<const float4*>(A1p);                          \
      paF1 = *reinterpret_cast<const float4*>(A1p + 4);                      \
    }                                                                        \
    if (A2 != nullptr)                                                       \
      pa2 = *reinterpret_cast<const uint4*>(A2 + aoff_row + (K0) + skg * 8); \
    pwh = *reinterpret_cast<const uint4*>(WhT + boff_row + (K0) + skg * 8);  \
    pwm = *reinterpret_cast<const uint4*>(WmT + boff_row + (K0) + skg * 8);  \
  } while (0)

#define STAGE()                                                              \
  do {                                                                       \
    float av[8];                                                             \
    if (a1bf) {                                                              \
      const unsigned int* pu = &paU.x;                                       \
      for (int j = 0; j < 4; ++j) {                                          \
        av[2 * j] = bf2f((unsigned short)(pu[j] & 0xffffu));                 \
        av[2 * j + 1] = bf2f((unsigned short)(pu[j] >> 16));                 \
      }                                                                      \
    } else {                                                                 \
      av[0] = paF0.x; av[1] = paF0.y; av[2] = paF0.z; av[3] = paF0.w;        \
      av[4] = paF1.x; av[5] = paF1.y; av[6] = paF1.z; av[7] = paF1.w;        \
    }                                                                        \
    if (A2 != nullptr) {                                                     \
      const unsigned int* pu = &pa2.x;                                       \
      for (int j = 0; j < 4; ++j) {                                          \
        av[2 * j] += bf2f((unsigned short)(pu[j] & 0xffffu));                \
        av[2 * j + 1] += bf2f((unsigned short)(pu[j] >> 16));                \
      }                                                                      \
    }                                                                        \
    unsigned int ph[4], pm[4];                                               \
    for (int j = 0; j < 4; ++j) {                                            \
      unsigned short h0 = f2bf(av[2 * j]);                                   \
      unsigned short h1 = f2bf(av[2 * j + 1]);                               \
      float r0 = av[2 * j] - bf2f(h0);                                       \
      float r1 = av[2 * j + 1] - bf2f(h1);                                   \
      ph[j] = (unsigned int)h0 | ((unsigned int)h1 << 16);                   \
      pm[j] = (unsigned int)f2bf(r0) | ((unsigned int)f2bf(r1) << 16);       \
    }                                                                        \
    uint4 vh; vh.x = ph[0]; vh.y = ph[1]; vh.z = ph[2]; vh.w = ph[3];        \
    uint4 vm; vm.x = pm[0]; vm.y = pm[1]; vm.z = pm[2]; vm.w = pm[3];        \
    *reinterpret_cast<uint4*>(smem + 0 + srow * 80 + skg * 16) = vh;         \
    *reinterpret_cast<uint4*>(smem + 5120 + srow * 80 + skg * 16) = vm;      \
    *reinterpret_cast<uint4*>(smem + 10240 + srow * 80 + skg * 16) = pwh;    \
    *reinterpret_cast<uint4*>(smem + 15360 + srow * 80 + skg * 16) = pwm;    \
  } while (0)

  const int aoff0 = (wr * 32 + lm) * 80 + quad * 16;
  const int aoff1 = aoff0 + 16 * 80;
  const int boff0 = (wcq * 32 + lm) * 80 + quad * 16;
  const int boff1 = boff0 + 16 * 80;

  LOAD_TILE(0);
  for (int k0 = 0; k0 < K; k0 += 32) {
    STAGE();
    __syncthreads();
    if (k0 + 32 < K) LOAD_TILE(k0 + 32);
    s16x8 aH0 = *reinterpret_cast<const s16x8*>(smem + 0 + aoff0);
    s16x8 aH1 = *reinterpret_cast<const s16x8*>(smem + 0 + aoff1);
    s16x8 bH0 = *reinterpret_cast<const s16x8*>(smem + 10240 + boff0);
    s16x8 bH1 = *reinterpret_cast<const s16x8*>(smem + 10240 + boff1);
    s16x8 bM0 = *reinterpret_cast<const s16x8*>(smem + 15360 + boff0);
    s16x8 bM1 = *reinterpret_cast<const s16x8*>(smem + 15360 + boff1);
    s16x8 aA0 = aH0 & (short)0x7FFF;
    s16x8 aA1 = aH1 & (short)0x7FFF;
    s16x8 bA0 = bH0 & (short)0x7FFF;
    s16x8 bA1 = bH1 & (short)0x7FFF;
    accH[0][0] = __builtin_amdgcn_mfma_f32_16x16x32_bf16(aH0, bH0, accH[0][0], 0, 0, 0);
    accH[0][1] = __builtin_amdgcn_mfma_f32_16x16x32_bf16(aH0, bH1, accH[0][1], 0, 0, 0);
    accH[1][0] = __builtin_amdgcn_mfma_f32_16x16x32_bf16(aH1, bH0, accH[1][0], 0, 0, 0);
    accH[1][1] = __builtin_amdgcn_mfma_f32_16x16x32_bf16(aH1, bH1, accH[1][1], 0, 0, 0);
    accM[0][0] = __builtin_amdgcn_mfma_f32_16x16x32_bf16(aH0, bM0, accM[0][0], 0, 0, 0);
    accM[0][1] = __builtin_amdgcn_mfma_f32_16x16x32_bf16(aH0, bM1, accM[0][1], 0, 0, 0);
    accM[1][0] = __builtin_amdgcn_mfma_f32_16x16x32_bf16(aH1, bM0, accM[1][0], 0, 0, 0);
    accM[1][1] = __builtin_amdgcn_mfma_f32_16x16x32_bf16(aH1, bM1, accM[1][1], 0, 0, 0);
    if (!a1bf) {
      s16x8 aM0 = *reinterpret_cast<const s16x8*>(smem + 5120 + aoff0);
      s16x8 aM1 = *reinterpret_cast<const s16x8*>(smem + 5120 + aoff1);
      accM[0][0] = __builtin_amdgcn_mfma_f32_16x16x32_bf16(aM0, bH0, accM[0][0], 0, 0, 0);
      accM[0][1] = __builtin_amdgcn_mfma_f32_16x16x32_bf16(aM0, bH1, accM[0][1], 0, 0, 0);
      accM[1][0] = __builtin_amdgcn_mfma_f32_16x16x32_bf16(aM1, bH0, accM[1][0], 0, 0, 0);
      accM[1][1] = __builtin_amdgcn_mfma_f32_16x16x32_bf16(aM1, bH1, accM[1][1], 0, 0, 0);
    }
    accA[0][0] = __builtin_amdgcn_mfma_f32_16x16x32_bf16(aA0, bA0, accA[0][0], 0, 0, 0);
    accA[0][1] = __builtin_amdgcn_mfma_f32_16x16x32_bf16(aA0, bA1, accA[0][1], 0, 0, 0);
    accA[1][0] = __builtin_amdgcn_mfma_f32_16x16x32_bf16(aA1, bA0, accA[1][0], 0, 0, 0);
    accA[1][1] = __builtin_amdgcn_mfma_f32_16x16x32_bf16(aA1, bA1, accA[1][1], 0, 0, 0);
    __syncthreads();
  }
#undef LOAD_TILE
#undef STAGE

  // ---- epilogue ----
  float* UXS = (float*)smem;
  float* UXA = (float*)(smem + 8192);
  if (wr == 1) {
#pragma unroll
    for (int mt = 0; mt < 2; ++mt)
#pragma unroll
      for (int nt = 0; nt < 2; ++nt)
#pragma unroll
        for (int j = 0; j < 4; ++j) {
          int i = mt * 8 + nt * 4 + j;
          UXS[i * 128 + wcq * 64 + lane] = accH[mt][nt][j] + accM[mt][nt][j];
          UXA[i * 128 + wcq * 64 + lane] = accA[mt][nt][j];
        }
  }
  __syncthreads();
  if (wr == 0) {
#pragma unroll
    for (int nt = 0; nt < 2; ++nt) {
      const int col = n0 + wcq * 32 + nt * 16 + lm;
      const double bb2 = (double)bias[col];
#pragma unroll
      for (int j = 0; j < 4; ++j) {
        const int bn = bn0 + quad * 4 + j;
        float sv[4], Ev[4];
        sv[0] = accH[0][nt][j] + accM[0][nt][j];
        sv[1] = accH[1][nt][j] + accM[1][nt][j];
        sv[2] = UXS[(0 * 8 + nt * 4 + j) * 128 + wcq * 64 + lane];
        sv[3] = UXS[(1 * 8 + nt * 4 + j) * 128 + wcq * 64 + lane];
        Ev[0] = errC * accA[0][nt][j];
        Ev[1] = errC * accA[1][nt][j];
        Ev[2] = errC * UXA[(0 * 8 + nt * 4 + j) * 128 + wcq * 64 + lane];
        Ev[3] = errC * UXA[(1 * 8 + nt * 4 + j) * 128 + wcq * 64 + lane];
        double v = 0.0;
        float errv = 0.f;
        bool flg = false;
        unsigned int spbits = 0;
#pragma unroll
        for (int t = 0; t < T_STEPS; ++t) {
          double u = (double)sv[t] + bb2;
          v = v + (u - v) * 0.5;
          errv = (errv + Ev[t]) * 0.5f;
          if (fabs(v - 1.0) < 2.0 * (double)errv + 1e-9) flg = true;
          float s = (v >= 1.0) ? 1.0f : 0.0f;
          if (v >= 1.0) { v = 0.0; errv = 0.f; }
          size_t idx = (size_t)(t * BN + bn) * N + col;
          if (mode == MODE_SPK) {
            ((unsigned short*)outv)[idx] = f2bf(s);
          } else if (mode == MODE_SPK_ADD) {
            float sp = bf2f(Sprev[idx]);
            if (sp != 0.f) spbits |= (1u << t);
            ((unsigned short*)outv)[idx] = f2bf(s + sp);
          } else {
            ((float*)outv)[idx] =
                (float)((double)Xres[idx] + (double)bf2f(S12[idx]) + (double)s);
          }
        }
        if (flg) {
          unsigned int rec = (unsigned int)(bn * N + col) |
                             ((unsigned int)sel << 22) | (spbits << 24);
          unsigned int ix = atomicAdd(cnt, 1u);
          if (ix < FLAG_CAP) flags[ix] = rec;
        }
      }
    }
  }
}

// ---------------------------------------------------------------------------
// f64 recompute of flagged neurons (exact vs reference). One wave per flag.
// ---------------------------------------------------------------------------
__global__ __launch_bounds__(256) void fix_k(
    const void* __restrict__ A1v, const unsigned short* __restrict__ A2,
    const float* __restrict__ WTa, const float* __restrict__ WTb,
    const float* __restrict__ WTc,
    const float* __restrict__ ba, const float* __restrict__ bb,
    const float* __restrict__ bc,
    const float* __restrict__ Xres, const unsigned short* __restrict__ S12,
    void* outa, void* outb, void* outc,
    const unsigned int* __restrict__ cnt, const unsigned int* __restrict__ flags,
    int N, int K, int mode, int a1bf) {
  unsigned int count = *cnt;
  if (count > FLAG_CAP) count = FLAG_CAP;
  const int lane = threadIdx.x & 63;
  const unsigned int wgid = blockIdx.x * 4 + (threadIdx.x >> 6);
  const unsigned int nw = gridDim.x * 4;
  for (unsigned int i = wgid; i < count; i += nw) {
    unsigned int rec = flags[i];
    int idxn = (int)(rec & 0x3FFFFFu);
    int sel = (int)((rec >> 22) & 3u);
    unsigned int spb = rec >> 24;
    int bn = idxn / N;
    int col = idxn - bn * N;
    const float* WT = sel == 0 ? WTa : (sel == 1 ? WTb : WTc);
    const float* bias = sel == 0 ? ba : (sel == 1 ? bb : bc);
    void* outv = sel == 0 ? outa : (sel == 1 ? outb : outc);
    double acc0 = 0, acc1 = 0, acc2 = 0, acc3 = 0;
    for (int k = lane; k < K; k += 64) {
      double w = (double)WT[(size_t)col * K + k];
      double a0, a1, a2, a3;
      if (a1bf) {
        const unsigned short* A1 = (const unsigned short*)A1v;
        a0 = (double)bf2f(A1[(size_t)(0 * BN + bn) * K + k]);
        a1 = (double)bf2f(A1[(size_t)(1 * BN + bn) * K + k]);
        a2 = (double)bf2f(A1[(size_t)(2 * BN + bn) * K + k]);
        a3 = (double)bf2f(A1[(size_t)(3 * BN + bn) * K + k]);
      } else {
        const float* A1 = (const float*)A1v;
        a0 = (double)A1[(size_t)(0 * BN + bn) * K + k];
        a1 = (double)A1[(size_t)(1 * BN + bn) * K + k];
        a2 = (double)A1[(size_t)(2 * BN + bn) * K + k];
        a3 = (double)A1[(size_t)(3 * BN + bn) * K + k];
      }
      if (A2 != nullptr) {
        a0 += (double)bf2f(A2[(size_t)(0 * BN + bn) * K + k]);
        a1 += (double)bf2f(A2[(size_t)(1 * BN + bn) * K + k]);
        a2 += (double)bf2f(A2[(size_t)(2 * BN + bn) * K + k]);
        a3 += (double)bf2f(A2[(size_t)(3 * BN + bn) * K + k]);
      }
      acc0 += a0 * w; acc1 += a1 * w; acc2 += a2 * w; acc3 += a3 * w;
    }
#pragma unroll
    for (int off = 32; off >= 1; off >>= 1) {
      acc0 += __shfl_down(acc0, off);
      acc1 += __shfl_down(acc1, off);
      acc2 += __shfl_down(acc2, off);
      acc3 += __shfl_down(acc3, off);
    }
    if (lane == 0) {
      double uu[4] = {acc0, acc1, acc2, acc3};
      double v = 0.0;
#pragma unroll
      for (int t = 0; t < T_STEPS; ++t) {
        double u = uu[t] + (double)bias[col];
        v = v + (u - v) * 0.5;
        float s = (v >= 1.0) ? 1.0f : 0.0f;
        if (v >= 1.0) v = 0.0;
        size_t idx = (size_t)(t * BN + bn) * N + col;
        if (mode == MODE_SPK) {
          ((unsigned short*)outv)[idx] = f2bf(s);
        } else if (mode == MODE_SPK_ADD) {
          ((unsigned short*)outv)[idx] =
              f2bf(s + (((spb >> t) & 1u) ? 1.0f : 0.0f));
        } else {
          ((float*)outv)[idx] =
              (float)((double)Xres[idx] + (double)bf2f(S12[idx]) + (double)s);
        }
      }
    }
  }
}

// ---------------------------------------------------------------------------
// Spiking attention, reassociated: u = 0.125 * q @ (k^T @ v). Exact int f32.
// ---------------------------------------------------------------------------
__global__ __launch_bounds__(256) void attn_k(const unsigned short* __restrict__ Q,
                                              const unsigned short* __restrict__ K,
                                              const unsigned short* __restrict__ V,
                                              float* __restrict__ O) {
  const int blk = blockIdx.x;
  const int h = blk & 7;
  const int tb = blk >> 3;
  const size_t base = (size_t)tb * (N_TOK * D_DIM) + h * 64;
  const int tid = threadIdx.x;
  const int tx = tid & 15, ty = tid >> 4;

  __shared__ float Kt[64][65];
  __shared__ float Vt[64][65];
  __shared__ float St[64][65];

  float S[4][4] = {};
  for (int mc = 0; mc < N_TOK; mc += 64) {
#pragma unroll
    for (int rr = 0; rr < 4; ++rr) {
      int row = rr * 16 + ty;
      ushort4 k4 = *reinterpret_cast<const ushort4*>(K + base + (size_t)(mc + row) * D_DIM + tx * 4);
      ushort4 v4 = *reinterpret_cast<const ushort4*>(V + base + (size_t)(mc + row) * D_DIM + tx * 4);
      Kt[row][tx * 4 + 0] = bf2f(k4.x); Kt[row][tx * 4 + 1] = bf2f(k4.y);
      Kt[row][tx * 4 + 2] = bf2f(k4.z); Kt[row][tx * 4 + 3] = bf2f(k4.w);
      Vt[row][tx * 4 + 0] = bf2f(v4.x); Vt[row][tx * 4 + 1] = bf2f(v4.y);
      Vt[row][tx * 4 + 2] = bf2f(v4.z); Vt[row][tx * 4 + 3] = bf2f(v4.w);
    }
    __syncthreads();
#pragma unroll 8
    for (int m = 0; m < 64; ++m) {
      float k0 = Kt[m][ty * 4 + 0], k1 = Kt[m][ty * 4 + 1];
      float k2 = Kt[m][ty * 4 + 2], k3 = Kt[m][ty * 4 + 3];
      float v0 = Vt[m][tx * 4 + 0], v1 = Vt[m][tx * 4 + 1];
      float v2 = Vt[m][tx * 4 + 2], v3 = Vt[m][tx * 4 + 3];
      S[0][0] += k0 * v0; S[0][1] += k0 * v1; S[0][2] += k0 * v2; S[0][3] += k0 * v3;
      S[1][0] += k1 * v0; S[1][1] += k1 * v1; S[1][2] += k1 * v2; S[1][3] += k1 * v3;
      S[2][0] += k2 * v0; S[2][1] += k2 * v1; S[2][2] += k2 * v2; S[2][3] += k2 * v3;
      S[3][0] += k3 * v0; S[3][1] += k3 * v1; S[3][2] += k3 * v2; S[3][3] += k3 * v3;
    }
    __syncthreads();
  }
#pragma unroll
  for (int i = 0; i < 4; ++i)
#pragma unroll
    for (int j = 0; j < 4; ++j) St[ty * 4 + i][tx * 4 + j] = S[i][j];
  __syncthreads();

  for (int nb = 0; nb < 8; ++nb) {
#pragma unroll
    for (int rr = 0; rr < 4; ++rr) {
      int row = rr * 16 + ty;
      ushort4 q4 = *reinterpret_cast<const ushort4*>(Q + base + (size_t)(nb * 64 + row) * D_DIM + tx * 4);
      Kt[row][tx * 4 + 0] = bf2f(q4.x); Kt[row][tx * 4 + 1] = bf2f(q4.y);
      Kt[row][tx * 4 + 2] = bf2f(q4.z); Kt[row][tx * 4 + 3] = bf2f(q4.w);
    }
    __syncthreads();
    float o[4][4] = {};
#pragma unroll 16
    for (int i = 0; i < 64; ++i) {
      float q0 = Kt[ty * 4 + 0][i], q1 = Kt[ty * 4 + 1][i];
      float q2 = Kt[ty * 4 + 2][i], q3 = Kt[ty * 4 + 3][i];
      float s0 = St[i][tx * 4 + 0], s1 = St[i][tx * 4 + 1];
      float s2 = St[i][tx * 4 + 2], s3 = St[i][tx * 4 + 3];
      o[0][0] += q0 * s0; o[0][1] += q0 * s1; o[0][2] += q0 * s2; o[0][3] += q0 * s3;
      o[1][0] += q1 * s0; o[1][1] += q1 * s1; o[1][2] += q1 * s2; o[1][3] += q1 * s3;
      o[2][0] += q2 * s0; o[2][1] += q2 * s1; o[2][2] += q2 * s2; o[2][3] += q2 * s3;
      o[3][0] += q3 * s0; o[3][1] += q3 * s1; o[3][2] += q3 * s2; o[3][3] += q3 * s3;
    }
#pragma unroll
    for (int r = 0; r < 4; ++r) {
      float4 ov;
      ov.x = o[r][0] * 0.125f; ov.y = o[r][1] * 0.125f;
      ov.z = o[r][2] * 0.125f; ov.w = o[r][3] * 0.125f;
      *reinterpret_cast<float4*>(O + base + (size_t)(nb * 64 + ty * 4 + r) * D_DIM + tx * 4) = ov;
    }
    __syncthreads();
  }
}

__global__ __launch_bounds__(256) void lif_plane(const float* __restrict__ U,
                                                 unsigned short* __restrict__ S) {
  int e = blockIdx.x * 256 + threadIdx.x;
  double v = 0.0;
#pragma unroll
  for (int t = 0; t < T_STEPS; ++t) {
    size_t idx = (size_t)t * (BN * D_DIM) + e;
    double u = (double)U[idx];
    v = v + (u - v) * 0.5;
    float s = (v >= 1.0) ? 1.0f : 0.0f;
    v = (v >= 1.0) ? 0.0 : v;
    S[idx] = f2bf(s);
  }
}

// ---------------------------------------------------------------------------
extern "C" void kernel_launch(void* const* d_in, const int* in_sizes, int n_in,
                              void* d_out, int out_size, void* d_ws, size_t ws_size,
                              hipStream_t stream) {
  const float* x    = (const float*)d_in[0];
  const float* enc  = (const float*)d_in[1];
  const float* Wq_s = (const float*)d_in[2];
  const float* bq_s = (const float*)d_in[3];
  const float* Wk_s = (const float*)d_in[4];
  const float* bk_s = (const float*)d_in[5];
  const float* Wv_s = (const float*)d_in[6];
  const float* bv_s = (const float*)d_in[7];
  const float* Wo_s = (const float*)d_in[8];
  const float* bo_s = (const float*)d_in[9];
  const float* Wq_c = (const float*)d_in[10];
  const float* bq_c = (const float*)d_in[11];
  const float* Wk_c = (const float*)d_in[12];
  const float* bk_c = (const float*)d_in[13];
  const float* Wv_c = (const float*)d_in[14];
  const float* bv_c = (const float*)d_in[15];
  const float* Wo_c = (const float*)d_in[16];
  const float* bo_c = (const float*)d_in[17];
  const float* W1   = (const float*)d_in[18];
  const float* b1   = (const float*)d_in[19];
  const float* W2   = (const float*)d_in[20];
  const float* b2   = (const float*)d_in[21];
  float* out = (float*)d_out;

  // ws layout (MB): 0-8 qs/as_; 8-40 ks,vs,u_attn (later h_spk over 8-40);
  // 40-48 s1; 48-65 WT f32; 65-74 WhT; 74-83 WmT; 83-91 flags; 91 counters.
  char* pool = (char*)d_ws;
  const size_t MB = 1024 * 1024;
  unsigned short* qs     = (unsigned short*)(pool + 0 * MB);
  unsigned short* ks     = (unsigned short*)(pool + 8 * MB);
  unsigned short* vs     = (unsigned short*)(pool + 16 * MB);
  float*          u_attn = (float*)(pool + 24 * MB);
  unsigned short* as_    = (unsigned short*)(pool + 0 * MB);
  unsigned short* h_spk  = (unsigned short*)(pool + 8 * MB);
  unsigned short* s1     = (unsigned short*)(pool + 40 * MB);
  float*          WT     = (float*)(pool + 48 * MB);
  unsigned short* WhT    = (unsigned short*)(pool + 65 * MB);
  unsigned short* WmT    = (unsigned short*)(pool + 74 * MB);
  unsigned int*   flags  = (unsigned int*)(pool + 83 * MB);
  unsigned int*   cnts   = (unsigned int*)(pool + 91 * MB);

  // element offsets of each matrix inside WT/WhT/WmT pools
  const size_t OQS = 0, OKS = 262144, OVS = 524288, OOS = 786432;
  const size_t OQC = 1048576, OKC = 1310720, OVC = 1572864, OOC = 1835008;
  const size_t OW1 = 2097152, OW2 = 3145728;

  const float ERR512 = 1.1f * 512.f * 5.96e-8f + 4.6e-5f;   // ~7.96e-5
  const float ERR2048 = 1.1f * 2048.f * 5.96e-8f + 4.6e-5f; // ~1.80e-4

  const unsigned short* NULS = nullptr;
  const float* NULF = nullptr;
  dim3 blk(256);
  int gLif = (BN * D_DIM) / 256;

  zero_k<<<1, 64, 0, stream>>>(cnts);
  wsplit_k<<<4096, blk, 0, stream>>>(Wq_s, Wk_s, Wv_s, Wo_s, Wq_c, Wk_c, Wv_c,
                                     Wo_c, W1, W2, WT, WhT, WmT);

  // ---- Block 1: self-attention ----
  gemm_ns<<<dim3(24, 128), blk, 0, stream>>>(
      x, NULS, WhT + OQS, WhT + OKS, WhT + OVS, WmT + OQS, WmT + OKS, WmT + OVS,
      bq_s, bk_s, bv_s, NULS, NULF, NULS, qs, ks, vs,
      cnts + 0, flags, 512, 512, 8, MODE_SPK, 0, ERR512);
  fix_k<<<128, blk, 0, stream>>>(x, NULS, WT + OQS, WT + OKS, WT + OVS,
      bq_s, bk_s, bv_s, NULF, NULS, qs, ks, vs, cnts + 0, flags, 512, 512, MODE_SPK, 0);
  attn_k<<<128, blk, 0, stream>>>(qs, ks, vs, u_attn);
  lif_plane<<<gLif, blk, 0, stream>>>(u_attn, as_);
  gemm_ns<<<dim3(8, 128), blk, 0, stream>>>(
      as_, NULS, WhT + OOS, WhT + OOS, WhT + OOS, WmT + OOS, WmT + OOS, WmT + OOS,
      bo_s, bo_s, bo_s, NULS, NULF, NULS, s1, s1, s1,
      cnts + 1, flags, 512, 512, 8, MODE_SPK, 1, ERR512);
  fix_k<<<128, blk, 0, stream>>>(as_, NULS, WT + OOS, WT + OOS, WT + OOS,
      bo_s, bo_s, bo_s, NULF, NULS, s1, s1, s1, cnts + 1, flags, 512, 512, MODE_SPK, 1);

  // ---- Block 2: cross-attention ----
  gemm_ns<<<dim3(8, 128), blk, 0, stream>>>(
      x, s1, WhT + OQC, WhT + OQC, WhT + OQC, WmT + OQC, WmT + OQC, WmT + OQC,
      bq_c, bq_c, bq_c, NULS, NULF, NULS, qs, qs, qs,
      cnts + 2, flags, 512, 512, 8, MODE_SPK, 0, ERR512);
  fix_k<<<128, blk, 0, stream>>>(x, s1, WT + OQC, WT + OQC, WT + OQC,
      bq_c, bq_c, bq_c, NULF, NULS, qs, qs, qs, cnts + 2, flags, 512, 512, MODE_SPK, 0);
  gemm_ns<<<dim3(16, 128), blk, 0, stream>>>(
      enc, NULS, WhT + OKC, WhT + OVC, WhT + OVC, WmT + OKC, WmT + OVC, WmT + OVC,
      bk_c, bv_c, bv_c, NULS, NULF, NULS, ks, vs, vs,
      cnts + 3, flags, 512, 512, 8, MODE_SPK, 0, ERR512);
  fix_k<<<128, blk, 0, stream>>>(enc, NULS, WT + OKC, WT + OVC, WT + OVC,
      bk_c, bv_c, bv_c, NULF, NULS, ks, vs, vs, cnts + 3, flags, 512, 512, MODE_SPK, 0);
  attn_k<<<128, blk, 0, stream>>>(qs, ks, vs, u_attn);
  lif_plane<<<gLif, blk, 0, stream>>>(u_attn, as_);
  gemm_ns<<<dim3(8, 128), blk, 0, stream>>>(
      as_, NULS, WhT + OOC, WhT + OOC, WhT + OOC, WmT + OOC, WmT + OOC, WmT + OOC,
      bo_c, bo_c, bo_c, s1, NULF, NULS, s1, s1, s1,
      cnts + 4, flags, 512, 512, 8, MODE_SPK_ADD, 1, ERR512);
  fix_k<<<128, blk, 0, stream>>>(as_, NULS, WT + OOC, WT + OOC, WT + OOC,
      bo_c, bo_c, bo_c, NULF, NULS, s1, s1, s1, cnts + 4, flags, 512, 512, MODE_SPK_ADD, 1);

  // ---- Block 3: spiking MLP ----
  gemm_ns<<<dim3(32, 128), blk, 0, stream>>>(
      x, s1, WhT + OW1, WhT + OW1, WhT + OW1, WmT + OW1, WmT + OW1, WmT + OW1,
      b1, b1, b1, NULS, NULF, NULS, h_spk, h_spk, h_spk,
      cnts + 5, flags, 2048, 512, 32, MODE_SPK, 0, ERR512);
  fix_k<<<128, blk, 0, stream>>>(x, s1, WT + OW1, WT + OW1, WT + OW1,
      b1, b1, b1, NULF, NULS, h_spk, h_spk, h_spk, cnts + 5, flags, 2048, 512, MODE_SPK, 0);
  gemm_ns<<<dim3(8, 128), blk, 0, stream>>>(
      h_spk, NULS, WhT + OW2, WhT + OW2, WhT + OW2, WmT + OW2, WmT + OW2, WmT + OW2,
      b2, b2, b2, NULS, x, s1, out, out, out,
      cnts + 6, flags, 512, 2048, 8, MODE_OUT, 1, ERR2048);
  fix_k<<<128, blk, 0, stream>>>(h_spk, NULS, WT + OW2, WT + OW2, WT + OW2,
      b2, b2, b2, x, s1, out, out, out, cnts + 6, flags, 512, 2048, MODE_OUT, 1);

  (void)in_sizes; (void)n_in; (void)out_size; (void)ws_size;
}